// Round 13
// baseline (104.637 us; speedup 1.0000x reference)
//
#include <hip/hip_runtime.h>

#define B_ 2
#define N_ 2048
#define M_ 2048
#define D_ 256
#define H_ 8
#define DH_ 32
#define SPLITS 2
#define REP 3  // instrumentation: replicate grids so dispatches exceed the fill
               // kernels' ~43us and show up in rocprof top-5 with counters.
               // Replicas do identical work -> identical stores (race-benign).
// 1/sqrt(32) * log2(e): fold into q projection; attention works in exp2 domain
#define QSCALE (0.17677669529663689f * 1.4426950408889634f)

typedef __attribute__((ext_vector_type(8))) short short8;
typedef __attribute__((ext_vector_type(4))) float f32x4;
typedef unsigned short u16;
typedef unsigned int u32;

#if __has_builtin(__builtin_amdgcn_exp2f)
#define EXP2 __builtin_amdgcn_exp2f
#else
#define EXP2 exp2f
#endif

__device__ __forceinline__ u16 f2bf(float f) {
  u32 u = __float_as_uint(f);
  return (u16)((u + 0x7fffu + ((u >> 16) & 1u)) >> 16);  // RNE
}
__device__ __forceinline__ u32 cvtpk_bf16(float lo, float hi) {
  u32 r;
  asm("v_cvt_pk_bf16_f32 %0, %1, %2" : "=v"(r) : "v"(lo), "v"(hi));
  return r;
}
__device__ __forceinline__ void gload_lds16(const u16* g, u16* l) {
  __builtin_amdgcn_global_load_lds((const __attribute__((address_space(1))) void*)g,
                                   (__attribute__((address_space(3))) void*)l, 16, 0, 0);
}

// ---------- K1: fused q/k/v projection (r7 version, best measured) ----------
__global__ __launch_bounds__(256, 2) void qkvproj_kernel(
    const float* __restrict__ Xq, const float* __restrict__ Xk, const float* __restrict__ Xv,
    const float* __restrict__ Wq, const float* __restrict__ Wk, const float* __restrict__ Wv,
    const float* __restrict__ bq, const float* __restrict__ bk, const float* __restrict__ bv,
    u16* __restrict__ qb, u16* __restrict__ kb, u16* __restrict__ vtb) {
  __shared__ u16 wsT[64 * 256];  // [c][k] = W[k][c], 16B-slot swizzle (k>>3)^(c&7)
  __shared__ u16 xs[64 * 256];   // [n][k] = X[n][k], swizzle (k>>3)^(n&7)
  const int p = blockIdx.y;      // blockIdx.z = replica (ignored)
  const int nb = blockIdx.x & 63, cb = blockIdx.x >> 6;
  const int n0B = nb * 64, c0B = cb * 64;
  const float* X = p == 0 ? Xq : (p == 1 ? Xk : Xv);
  const float* W = p == 0 ? Wq : (p == 1 ? Wk : Wv);
  const float* bias = p == 0 ? bq : (p == 1 ? bk : bv);
  const int t = threadIdx.x;

  {  // stage W^T
    const int cL = (t & 15) * 4, kB = (t >> 4) * 16;
    const float* wp = W + (size_t)kB * D_ + c0B + cL;
#pragma unroll
    for (int u = 0; u < 4; ++u) {
      const int k0 = kB + 4 * u;
      const f32x4 w0 = *(const f32x4*)(wp + (size_t)(4 * u + 0) * D_);
      const f32x4 w1 = *(const f32x4*)(wp + (size_t)(4 * u + 1) * D_);
      const f32x4 w2 = *(const f32x4*)(wp + (size_t)(4 * u + 2) * D_);
      const f32x4 w3 = *(const f32x4*)(wp + (size_t)(4 * u + 3) * D_);
#pragma unroll
      for (int cc = 0; cc < 4; ++cc) {
        const int c = cL + cc;
        uint2 v;
        v.x = cvtpk_bf16(w0[cc], w1[cc]);
        v.y = cvtpk_bf16(w2[cc], w3[cc]);
        *(uint2*)(wsT + c * 256 + (((k0 >> 3) ^ (c & 7)) * 8) + (k0 & 7)) = v;
      }
    }
  }
  {  // stage X
    const int nL = t >> 2, k64 = (t & 3) * 64;
    const float* xp = X + (size_t)(n0B + nL) * D_ + k64;
#pragma unroll
    for (int m = 0; m < 8; ++m) {
      const f32x4 a = *(const f32x4*)(xp + 8 * m);
      const f32x4 b2 = *(const f32x4*)(xp + 8 * m + 4);
      uint4 v;
      v.x = cvtpk_bf16(a[0], a[1]);
      v.y = cvtpk_bf16(a[2], a[3]);
      v.z = cvtpk_bf16(b2[0], b2[1]);
      v.w = cvtpk_bf16(b2[2], b2[3]);
      const int k0 = k64 + 8 * m;
      *(uint4*)(xs + nL * 256 + (((k0 >> 3) ^ (nL & 7)) * 8)) = v;
    }
  }
  __syncthreads();

  const int wv = t >> 6, lane = t & 63, lr = lane & 15, lg = lane >> 4;
  const f32x4 zz = {0.f, 0.f, 0.f, 0.f};
  f32x4 acc[4] = {zz, zz, zz, zz};
  const int arow = wv * 16 + lr;
#pragma unroll
  for (int ks = 0; ks < 8; ++ks) {
    const short8 a = *(const short8*)(wsT + arow * 256 + (((ks * 4 + lg) ^ (arow & 7)) * 8));
#pragma unroll
    for (int ng = 0; ng < 4; ++ng) {
      const int brow = ng * 16 + lr;
      const short8 b = *(const short8*)(xs + brow * 256 + (((ks * 4 + lg) ^ (brow & 7)) * 8));
      acc[ng] = __builtin_amdgcn_mfma_f32_16x16x32_bf16(a, b, acc[ng], 0, 0, 0);
    }
  }

  // D layout: col(lr)=n, row(lg*4+j)=c
  const int cg4 = c0B + wv * 16 + lg * 4;
  const f32x4 bias4 = *(const f32x4*)(bias + cg4);
  if (p < 2) {
    u16* ob = p == 0 ? qb : kb;
    const float sc = p == 0 ? QSCALE : 1.0f;
#pragma unroll
    for (int ng = 0; ng < 4; ++ng) {
      const int n = n0B + ng * 16 + lr;
      const int b = n >> 11, nn = n & (N_ - 1);
#pragma unroll
      for (int j = 0; j < 4; ++j) {
        const int c = cg4 + j;
        ob[((size_t)(b * H_ + (c >> 5)) * N_ + nn) * DH_ + (c & 31)] =
            f2bf((acc[ng][j] + bias4[j]) * sc);
      }
    }
  } else {
#pragma unroll
    for (int ng = 0; ng < 4; ++ng) {
      const int n = n0B + ng * 16 + lr;
      const int b = n >> 11, nn = n & (M_ - 1);
#pragma unroll
      for (int j = 0; j < 4; ++j) {
        const int c = cg4 + j;
        vtb[((size_t)(b * H_ + (c >> 5)) * DH_ + (c & 31)) * M_ + nn] =
            f2bf(acc[ng][j] + bias4[j]);
      }
    }
  }
}

// ---------- K2: flash attention (r7 body verbatim, key-split 2) ----------
__global__ __launch_bounds__(256, 4) void attn_kernel(
    const u16* __restrict__ qb, const u16* __restrict__ kb,
    const u16* __restrict__ vtb, const float* __restrict__ presence,
    float* __restrict__ opart, float* __restrict__ lpart) {
  __shared__ u16 kvlds[2][4096];  // [buf]: K[64 keys][32 d] swz | V[32 d][64 keys] swz
  __shared__ u16 plds[4][1024];   // per-wave P tile [16 q][64 k], swizzled
  const int t = threadIdx.x;
  const int wv = t >> 6, lane = t & 63;
  const int lr = lane & 15, lg = lane >> 4;
  const int base = blockIdx.x & 1023;  // replica bits above bit 9 ignored
  const int s = base >> 9;
  const int bh = (base >> 5) & 15;
  const int qblk = base & 31;
  const int b = bh >> 3, h = bh & 7;
  const int n0 = qblk * 64 + wv * 16;
  const int m0 = s * (M_ / SPLITS);
  const int NI = (M_ / SPLITS) / 64;  // 16 chunks

  // staging sources (per-lane, pre-swizzled)
  const int gsk = (t & 3) ^ ((t >> 3) & 3);
  const u16* kst = kb + ((size_t)bh * M_ + m0 + (t >> 2)) * DH_ + gsk * 8;
  const int gsv = (t & 7) ^ ((t >> 3) & 7);
  const u16* vst = vtb + ((size_t)bh * DH_ + (t >> 3)) * M_ + m0 + gsv * 8;
  u16* const ldswK = &kvlds[0][0] + wv * 512;         // + buf*4096
  u16* const ldswV = &kvlds[0][0] + 2048 + wv * 512;  // + buf*4096

  // per-lane LDS fragment read offsets (u16 units)
  const int ko0 = lr * 32 + (lg ^ ((lr >> 1) & 3)) * 8;  // K: + tt*512
  const int sw = lr & 7;
  const int vo0 = (lg ^ sw) * 8;        // keys lg*8
  const int vo1 = ((4 + lg) ^ sw) * 8;  // keys 32+lg*8

  // Q as B-frag of S^T: col=query=lr, k=d=lg*8+j
  const short8 qf = *(const short8*)(qb + ((size_t)bh * N_ + n0 + lr) * DH_ + lg * 8);
  const float* pbase = presence + (size_t)b * M_ + m0 + lg * 4;
  u16* const plw = plds[wv] + lr * 64;

  const f32x4 zz = {0.f, 0.f, 0.f, 0.f};
  f32x4 o0 = zz, o1 = zz, racc = zz;

  gload_lds16(kst, ldswK);  // chunk 0 -> buf 0
  gload_lds16(vst, ldswV);
  __syncthreads();

#pragma unroll 2
  for (int i = 0; i < NI; ++i) {
    const int mm = i * 64;
    const u16* kl = &kvlds[i & 1][0];
    const u16* vl = &kvlds[i & 1][2048];
    // presence first (its vmcnt wait must not drain the stage-DMA below)
    f32x4 pr[4];
#pragma unroll
    for (int tt = 0; tt < 4; ++tt) pr[tt] = *(const f32x4*)(pbase + mm + tt * 16);
    if (i + 1 < NI) {  // prefetch chunk i+1 into other buffer
      const int bo = ((i + 1) & 1) * 4096;
      gload_lds16(kst + (size_t)(i + 1) * (64 * DH_), ldswK + bo);
      gload_lds16(vst + (size_t)(i + 1) * 64, ldswV + bo);
    }

    f32x4 s4[4];
    __builtin_amdgcn_s_setprio(1);
#pragma unroll
    for (int tt = 0; tt < 4; ++tt) {
      const short8 kf = *(const short8*)(kl + tt * 512 + ko0);
      s4[tt] = __builtin_amdgcn_mfma_f32_16x16x32_bf16(kf, qf, zz, 0, 0, 0);
    }
    __builtin_amdgcn_s_setprio(0);

#pragma unroll
    for (int tt = 0; tt < 4; ++tt) {
      s4[tt] += (pr[tt] - 1.f) * 1e30f;  // exact 0 present / -1e30 masked
#pragma unroll
      for (int j = 0; j < 4; ++j) s4[tt][j] = EXP2(s4[tt][j]);
      racc += s4[tt];
      const int slot = (2 * tt + (lg >> 1)) ^ sw;
      *(uint2*)(plw + slot * 8 + (lg & 1) * 4) =
          make_uint2(cvtpk_bf16(s4[tt][0], s4[tt][1]), cvtpk_bf16(s4[tt][2], s4[tt][3]));
    }
    // immediate PV (wave-private P tile; compiler orders via lgkmcnt)
    const short8 pf0 = *(const short8*)(plw + vo0);
    const short8 pf1 = *(const short8*)(plw + vo1);
    const short8 vf0 = *(const short8*)(vl + lr * 64 + vo0);
    const short8 vf1 = *(const short8*)(vl + lr * 64 + vo1);
    const short8 vf2 = *(const short8*)(vl + (16 + lr) * 64 + vo0);
    const short8 vf3 = *(const short8*)(vl + (16 + lr) * 64 + vo1);
    __builtin_amdgcn_s_setprio(1);
    o0 = __builtin_amdgcn_mfma_f32_16x16x32_bf16(pf0, vf0, o0, 0, 0, 0);
    o0 = __builtin_amdgcn_mfma_f32_16x16x32_bf16(pf1, vf1, o0, 0, 0, 0);
    o1 = __builtin_amdgcn_mfma_f32_16x16x32_bf16(pf0, vf2, o1, 0, 0, 0);
    o1 = __builtin_amdgcn_mfma_f32_16x16x32_bf16(pf1, vf3, o1, 0, 0, 0);
    __builtin_amdgcn_s_setprio(0);
    __syncthreads();
  }

  float l = (racc[0] + racc[1]) + (racc[2] + racc[3]);
  l += __shfl_xor(l, 16);
  l += __shfl_xor(l, 32);
  if (lg == 0) lpart[((size_t)s * (B_ * N_) + b * N_ + n0 + lr) * H_ + h] = l;

  float* ob = opart + ((size_t)s * (B_ * N_) + (size_t)b * N_ + n0) * D_ + h * DH_;
#pragma unroll
  for (int j = 0; j < 4; ++j) {
    const int q = lg * 4 + j;
    ob[(size_t)q * D_ + lr] = o0[j];
    ob[(size_t)q * D_ + 16 + lr] = o1[j];
  }
}

// ---------- K3: output projection (combine 2 splits, normalize, MFMA) ----------
__global__ __launch_bounds__(256, 2) void projo_kernel(
    const float* __restrict__ opart, const float* __restrict__ lpart,
    const float* __restrict__ Wo, const float* __restrict__ bo,
    float* __restrict__ out) {
  __shared__ u16 wsT[64 * 256];  // Wo^T [c][k] swizzled
  __shared__ u16 xs[64 * 256];   // normalized attention output [n][k] swizzled
  const int base = blockIdx.x & 255;  // replica bits ignored
  const int nb = base & 63, cb = base >> 6;
  const int n0B = nb * 64, c0B = cb * 64;
  const int t = threadIdx.x;

  {  // stage Wo^T
    const int cL = (t & 15) * 4, kB = (t >> 4) * 16;
    const float* wp = Wo + (size_t)kB * D_ + c0B + cL;
#pragma unroll
    for (int u = 0; u < 4; ++u) {
      const int k0 = kB + 4 * u;
      const f32x4 w0 = *(const f32x4*)(wp + (size_t)(4 * u + 0) * D_);
      const f32x4 w1 = *(const f32x4*)(wp + (size_t)(4 * u + 1) * D_);
      const f32x4 w2 = *(const f32x4*)(wp + (size_t)(4 * u + 2) * D_);
      const f32x4 w3 = *(const f32x4*)(wp + (size_t)(4 * u + 3) * D_);
#pragma unroll
      for (int cc = 0; cc < 4; ++cc) {
        const int c = cL + cc;
        uint2 v;
        v.x = cvtpk_bf16(w0[cc], w1[cc]);
        v.y = cvtpk_bf16(w2[cc], w3[cc]);
        *(uint2*)(wsT + c * 256 + (((k0 >> 3) ^ (c & 7)) * 8) + (k0 & 7)) = v;
      }
    }
  }
  {  // stage A = (opart0 + opart1) * (1/l), bf16 swizzled
    const int nL = t >> 2, k64 = (t & 3) * 64;
    const int gn = n0B + nL;
    const int h0 = k64 >> 5;
    float l0s = 0.f, l1s = 0.f;
#pragma unroll
    for (int sp = 0; sp < SPLITS; ++sp) {
      l0s += lpart[((size_t)sp * (B_ * N_) + gn) * H_ + h0];
      l1s += lpart[((size_t)sp * (B_ * N_) + gn) * H_ + h0 + 1];
    }
    const float il0 = 1.f / l0s, il1 = 1.f / l1s;
    const float* obase = opart + (size_t)gn * D_ + k64;
#pragma unroll
    for (int m = 0; m < 8; ++m) {
      f32x4 a = {0.f, 0.f, 0.f, 0.f};
      f32x4 b2 = {0.f, 0.f, 0.f, 0.f};
#pragma unroll
      for (int sp = 0; sp < SPLITS; ++sp) {
        const float* op = obase + (size_t)sp * (B_ * N_) * D_;
        a += *(const f32x4*)(op + 8 * m);
        b2 += *(const f32x4*)(op + 8 * m + 4);
      }
      const float il = (m < 4) ? il0 : il1;
      a *= il;
      b2 *= il;
      uint4 v;
      v.x = cvtpk_bf16(a[0], a[1]);
      v.y = cvtpk_bf16(a[2], a[3]);
      v.z = cvtpk_bf16(b2[0], b2[1]);
      v.w = cvtpk_bf16(b2[2], b2[3]);
      const int k0 = k64 + 8 * m;
      *(uint4*)(xs + nL * 256 + (((k0 >> 3) ^ (nL & 7)) * 8)) = v;
    }
  }
  __syncthreads();

  const int wv = t >> 6, lane = t & 63, lr = lane & 15, lg = lane >> 4;
  const f32x4 zz = {0.f, 0.f, 0.f, 0.f};
  f32x4 acc[4] = {zz, zz, zz, zz};
  const int arow = wv * 16 + lr;
#pragma unroll
  for (int ks = 0; ks < 8; ++ks) {
    const short8 a = *(const short8*)(xs + arow * 256 + (((ks * 4 + lg) ^ (arow & 7)) * 8));
#pragma unroll
    for (int ng = 0; ng < 4; ++ng) {
      const int brow = ng * 16 + lr;
      const short8 bfr = *(const short8*)(wsT + brow * 256 + (((ks * 4 + lg) ^ (brow & 7)) * 8));
      acc[ng] = __builtin_amdgcn_mfma_f32_16x16x32_bf16(a, bfr, acc[ng], 0, 0, 0);
    }
  }
  // D layout: col(lr)=c, row(lg*4+j)=n -> coalesced f32 stores
#pragma unroll
  for (int ng = 0; ng < 4; ++ng) {
    const int c = c0B + ng * 16 + lr;
    const float bb = bo[c];
#pragma unroll
    for (int j = 0; j < 4; ++j)
      out[(size_t)(n0B + wv * 16 + lg * 4 + j) * D_ + c] = acc[ng][j] + bb;
  }
}

extern "C" void kernel_launch(void* const* d_in, const int* in_sizes, int n_in,
                              void* d_out, int out_size, void* d_ws, size_t ws_size,
                              hipStream_t stream) {
  (void)in_sizes; (void)n_in; (void)out_size; (void)ws_size;
  const float* queries  = (const float*)d_in[0];
  const float* keys     = (const float*)d_in[1];
  const float* values   = (const float*)d_in[2];
  const float* presence = (const float*)d_in[3];
  const float* Wq = (const float*)d_in[4];
  const float* bq = (const float*)d_in[5];
  const float* Wk = (const float*)d_in[6];
  const float* bk = (const float*)d_in[7];
  const float* Wv = (const float*)d_in[8];
  const float* bv = (const float*)d_in[9];
  const float* Wo = (const float*)d_in[10];
  const float* bo = (const float*)d_in[11];

  // ws: qb 2MB | kb 2MB | vtb 2MB | opart 8MB | lpart 256KB
  u16* qb  = (u16*)d_ws;
  u16* kb  = qb + (size_t)B_ * H_ * N_ * DH_;
  u16* vtb = kb + (size_t)B_ * H_ * M_ * DH_;
  float* opart = (float*)(vtb + (size_t)B_ * H_ * DH_ * M_);
  float* lpart = opart + (size_t)SPLITS * B_ * N_ * D_;

  qkvproj_kernel<<<dim3(256, 3, REP), 256, 0, stream>>>(
      queries, keys, values, Wq, Wk, Wv, bq, bk, bv, qb, kb, vtb);
  attn_kernel<<<REP * SPLITS * 16 * 32, 256, 0, stream>>>(qb, kb, vtb, presence, opart, lpart);
  projo_kernel<<<REP * 256, 256, 0, stream>>>(opart, lpart, Wo, bo, (float*)d_out);
}

// Round 14
// 46.156 us; speedup vs baseline: 2.2670x; 2.2670x over previous
//
#include <hip/hip_runtime.h>

#define B_ 2
#define N_ 2048
#define M_ 2048
#define D_ 256
#define H_ 8
#define DH_ 32
#define SPLITS 2
// 1/sqrt(32) * log2(e): fold into q projection; attention works in exp2 domain
#define QSCALE (0.17677669529663689f * 1.4426950408889634f)

typedef __attribute__((ext_vector_type(8))) short short8;
typedef __attribute__((ext_vector_type(4))) float f32x4;
typedef unsigned short u16;
typedef unsigned int u32;

#if __has_builtin(__builtin_amdgcn_exp2f)
#define EXP2 __builtin_amdgcn_exp2f
#else
#define EXP2 exp2f
#endif

__device__ __forceinline__ u16 f2bf(float f) {
  u32 u = __float_as_uint(f);
  return (u16)((u + 0x7fffu + ((u >> 16) & 1u)) >> 16);  // RNE
}
__device__ __forceinline__ u32 cvtpk_bf16(float lo, float hi) {
  u32 r;
  asm("v_cvt_pk_bf16_f32 %0, %1, %2" : "=v"(r) : "v"(lo), "v"(hi));
  return r;
}
__device__ __forceinline__ void gload_lds16(const u16* g, u16* l) {
  __builtin_amdgcn_global_load_lds((const __attribute__((address_space(1))) void*)g,
                                   (__attribute__((address_space(3))) void*)l, 16, 0, 0);
}
__device__ __forceinline__ void gload_lds16f(const float* g, float* l) {
  __builtin_amdgcn_global_load_lds((const __attribute__((address_space(1))) void*)g,
                                   (__attribute__((address_space(3))) void*)l, 16, 0, 0);
}

// ---------- K1: fused q/k/v projection (r7 version, best measured) ----------
__global__ __launch_bounds__(256, 2) void qkvproj_kernel(
    const float* __restrict__ Xq, const float* __restrict__ Xk, const float* __restrict__ Xv,
    const float* __restrict__ Wq, const float* __restrict__ Wk, const float* __restrict__ Wv,
    const float* __restrict__ bq, const float* __restrict__ bk, const float* __restrict__ bv,
    u16* __restrict__ qb, u16* __restrict__ kb, u16* __restrict__ vtb) {
  __shared__ u16 wsT[64 * 256];  // [c][k] = W[k][c], 16B-slot swizzle (k>>3)^(c&7)
  __shared__ u16 xs[64 * 256];   // [n][k] = X[n][k], swizzle (k>>3)^(n&7)
  const int p = blockIdx.y;
  const int nb = blockIdx.x & 63, cb = blockIdx.x >> 6;
  const int n0B = nb * 64, c0B = cb * 64;
  const float* X = p == 0 ? Xq : (p == 1 ? Xk : Xv);
  const float* W = p == 0 ? Wq : (p == 1 ? Wk : Wv);
  const float* bias = p == 0 ? bq : (p == 1 ? bk : bv);
  const int t = threadIdx.x;

  {  // stage W^T
    const int cL = (t & 15) * 4, kB = (t >> 4) * 16;
    const float* wp = W + (size_t)kB * D_ + c0B + cL;
#pragma unroll
    for (int u = 0; u < 4; ++u) {
      const int k0 = kB + 4 * u;
      const f32x4 w0 = *(const f32x4*)(wp + (size_t)(4 * u + 0) * D_);
      const f32x4 w1 = *(const f32x4*)(wp + (size_t)(4 * u + 1) * D_);
      const f32x4 w2 = *(const f32x4*)(wp + (size_t)(4 * u + 2) * D_);
      const f32x4 w3 = *(const f32x4*)(wp + (size_t)(4 * u + 3) * D_);
#pragma unroll
      for (int cc = 0; cc < 4; ++cc) {
        const int c = cL + cc;
        uint2 v;
        v.x = cvtpk_bf16(w0[cc], w1[cc]);
        v.y = cvtpk_bf16(w2[cc], w3[cc]);
        *(uint2*)(wsT + c * 256 + (((k0 >> 3) ^ (c & 7)) * 8) + (k0 & 7)) = v;
      }
    }
  }
  {  // stage X
    const int nL = t >> 2, k64 = (t & 3) * 64;
    const float* xp = X + (size_t)(n0B + nL) * D_ + k64;
#pragma unroll
    for (int m = 0; m < 8; ++m) {
      const f32x4 a = *(const f32x4*)(xp + 8 * m);
      const f32x4 b2 = *(const f32x4*)(xp + 8 * m + 4);
      uint4 v;
      v.x = cvtpk_bf16(a[0], a[1]);
      v.y = cvtpk_bf16(a[2], a[3]);
      v.z = cvtpk_bf16(b2[0], b2[1]);
      v.w = cvtpk_bf16(b2[2], b2[3]);
      const int k0 = k64 + 8 * m;
      *(uint4*)(xs + nL * 256 + (((k0 >> 3) ^ (nL & 7)) * 8)) = v;
    }
  }
  __syncthreads();

  const int wv = t >> 6, lane = t & 63, lr = lane & 15, lg = lane >> 4;
  const f32x4 zz = {0.f, 0.f, 0.f, 0.f};
  f32x4 acc[4] = {zz, zz, zz, zz};
  const int arow = wv * 16 + lr;
#pragma unroll
  for (int ks = 0; ks < 8; ++ks) {
    const short8 a = *(const short8*)(wsT + arow * 256 + (((ks * 4 + lg) ^ (arow & 7)) * 8));
#pragma unroll
    for (int ng = 0; ng < 4; ++ng) {
      const int brow = ng * 16 + lr;
      const short8 b = *(const short8*)(xs + brow * 256 + (((ks * 4 + lg) ^ (brow & 7)) * 8));
      acc[ng] = __builtin_amdgcn_mfma_f32_16x16x32_bf16(a, b, acc[ng], 0, 0, 0);
    }
  }

  // D layout: col(lr)=n, row(lg*4+j)=c
  const int cg4 = c0B + wv * 16 + lg * 4;
  const f32x4 bias4 = *(const f32x4*)(bias + cg4);
  if (p < 2) {
    u16* ob = p == 0 ? qb : kb;
    const float sc = p == 0 ? QSCALE : 1.0f;
#pragma unroll
    for (int ng = 0; ng < 4; ++ng) {
      const int n = n0B + ng * 16 + lr;
      const int b = n >> 11, nn = n & (N_ - 1);
#pragma unroll
      for (int j = 0; j < 4; ++j) {
        const int c = cg4 + j;
        ob[((size_t)(b * H_ + (c >> 5)) * N_ + nn) * DH_ + (c & 31)] =
            f2bf((acc[ng][j] + bias4[j]) * sc);
      }
    }
  } else {
#pragma unroll
    for (int ng = 0; ng < 4; ++ng) {
      const int n = n0B + ng * 16 + lr;
      const int b = n >> 11, nn = n & (M_ - 1);
#pragma unroll
      for (int j = 0; j < 4; ++j) {
        const int c = cg4 + j;
        vtb[((size_t)(b * H_ + (c >> 5)) * DH_ + (c & 31)) * M_ + nn] =
            f2bf(acc[ng][j] + bias4[j]);
      }
    }
  }
}

// ---------- K2: flash attention (r9-attn: presence in LDS, multiplicative mask) ----
// grid = 2 splits x 16 bh x 32 qtiles = 1024 blocks (4/CU); 4 waves, 16 q each.
__global__ __launch_bounds__(256, 4) void attn_kernel(
    const u16* __restrict__ qb, const u16* __restrict__ kb,
    const u16* __restrict__ vtb, const float* __restrict__ presence,
    float* __restrict__ opart, float* __restrict__ lpart) {
  __shared__ u16 kvlds[2][4096];  // [buf]: K[64 keys][32 d] swz | V[32 d][64 keys] swz
  __shared__ u16 plds[4][1024];   // per-wave P tile [16 q][64 k], swizzled
  __shared__ float prlds[1024];   // presence slice (f32)
  const int t = threadIdx.x;
  const int wv = t >> 6, lane = t & 63;
  const int lr = lane & 15, lg = lane >> 4;
  const int s = blockIdx.x >> 9;
  const int bh = (blockIdx.x >> 5) & 15;
  const int qblk = blockIdx.x & 31;
  const int b = bh >> 3, h = bh & 7;
  const int n0 = qblk * 64 + wv * 16;
  const int m0 = s * (M_ / SPLITS);
  const int NI = (M_ / SPLITS) / 64;  // 16 chunks

  // staging sources (per-lane, pre-swizzled)
  const int gsk = (t & 3) ^ ((t >> 3) & 3);
  const u16* kst = kb + ((size_t)bh * M_ + m0 + (t >> 2)) * DH_ + gsk * 8;
  const int gsv = (t & 7) ^ ((t >> 3) & 7);
  const u16* vst = vtb + ((size_t)bh * DH_ + (t >> 3)) * M_ + m0 + gsv * 8;
  u16* const ldswK = &kvlds[0][0] + wv * 512;         // + buf*4096
  u16* const ldswV = &kvlds[0][0] + 2048 + wv * 512;  // + buf*4096

  // per-lane LDS fragment read offsets (u16 units)
  const int ko0 = lr * 32 + (lg ^ ((lr >> 1) & 3)) * 8;  // K: + tt*512
  const int sw = lr & 7;
  const int vo0 = (lg ^ sw) * 8;        // keys lg*8
  const int vo1 = ((4 + lg) ^ sw) * 8;  // keys 32+lg*8

  // Q as B-frag of S^T: col=query=lr, k=d=lg*8+j
  const short8 qf = *(const short8*)(qb + ((size_t)bh * N_ + n0 + lr) * DH_ + lg * 8);
  u16* const plw = plds[wv] + lr * 64;

  const f32x4 zz = {0.f, 0.f, 0.f, 0.f};
  f32x4 o0 = zz, o1 = zz, racc = zz;

  gload_lds16(kst, ldswK);  // chunk 0 -> buf 0
  gload_lds16(vst, ldswV);
  gload_lds16f(presence + (size_t)b * M_ + m0 + wv * 256 + lane * 4, prlds + wv * 256);
  __syncthreads();

#pragma unroll 2
  for (int i = 0; i < NI; ++i) {
    const int mm = i * 64;
    const u16* kl = &kvlds[i & 1][0];
    const u16* vl = &kvlds[i & 1][2048];
    if (i + 1 < NI) {  // prefetch chunk i+1 into other buffer
      const int bo = ((i + 1) & 1) * 4096;
      gload_lds16(kst + (size_t)(i + 1) * (64 * DH_), ldswK + bo);
      gload_lds16(vst + (size_t)(i + 1) * 64, ldswV + bo);
    }

    f32x4 s4[4];
    __builtin_amdgcn_s_setprio(1);
#pragma unroll
    for (int tt = 0; tt < 4; ++tt) {
      const short8 kf = *(const short8*)(kl + tt * 512 + ko0);
      s4[tt] = __builtin_amdgcn_mfma_f32_16x16x32_bf16(kf, qf, zz, 0, 0, 0);
    }
    __builtin_amdgcn_s_setprio(0);

#pragma unroll
    for (int tt = 0; tt < 4; ++tt) {
      const f32x4 pr = *(const f32x4*)(prlds + mm + tt * 16 + lg * 4);  // broadcast
#pragma unroll
      for (int j = 0; j < 4; ++j) s4[tt][j] = EXP2(s4[tt][j]);
      s4[tt] *= pr;  // exact 0 when masked, identity when present
      racc += s4[tt];
      const int slot = (2 * tt + (lg >> 1)) ^ sw;
      *(uint2*)(plw + slot * 8 + (lg & 1) * 4) =
          make_uint2(cvtpk_bf16(s4[tt][0], s4[tt][1]), cvtpk_bf16(s4[tt][2], s4[tt][3]));
    }
    // immediate PV (wave-private P tile; compiler orders via lgkmcnt)
    const short8 pf0 = *(const short8*)(plw + vo0);
    const short8 pf1 = *(const short8*)(plw + vo1);
    const short8 vf0 = *(const short8*)(vl + lr * 64 + vo0);
    const short8 vf1 = *(const short8*)(vl + lr * 64 + vo1);
    const short8 vf2 = *(const short8*)(vl + (16 + lr) * 64 + vo0);
    const short8 vf3 = *(const short8*)(vl + (16 + lr) * 64 + vo1);
    __builtin_amdgcn_s_setprio(1);
    o0 = __builtin_amdgcn_mfma_f32_16x16x32_bf16(pf0, vf0, o0, 0, 0, 0);
    o0 = __builtin_amdgcn_mfma_f32_16x16x32_bf16(pf1, vf1, o0, 0, 0, 0);
    o1 = __builtin_amdgcn_mfma_f32_16x16x32_bf16(pf0, vf2, o1, 0, 0, 0);
    o1 = __builtin_amdgcn_mfma_f32_16x16x32_bf16(pf1, vf3, o1, 0, 0, 0);
    __builtin_amdgcn_s_setprio(0);
    __syncthreads();
  }

  float l = (racc[0] + racc[1]) + (racc[2] + racc[3]);
  l += __shfl_xor(l, 16);
  l += __shfl_xor(l, 32);
  if (lg == 0) lpart[((size_t)s * (B_ * N_) + b * N_ + n0 + lr) * H_ + h] = l;

  float* ob = opart + ((size_t)s * (B_ * N_) + (size_t)b * N_ + n0) * D_ + h * DH_;
#pragma unroll
  for (int j = 0; j < 4; ++j) {
    const int q = lg * 4 + j;
    ob[(size_t)q * D_ + lr] = o0[j];
    ob[(size_t)q * D_ + 16 + lr] = o1[j];
  }
}

// ---------- K3: output projection (combine 2 splits, normalize, MFMA) ----------
__global__ __launch_bounds__(256, 2) void projo_kernel(
    const float* __restrict__ opart, const float* __restrict__ lpart,
    const float* __restrict__ Wo, const float* __restrict__ bo,
    float* __restrict__ out) {
  __shared__ u16 wsT[64 * 256];  // Wo^T [c][k] swizzled
  __shared__ u16 xs[64 * 256];   // normalized attention output [n][k] swizzled
  const int nb = blockIdx.x & 63, cb = blockIdx.x >> 6;
  const int n0B = nb * 64, c0B = cb * 64;
  const int t = threadIdx.x;

  {  // stage Wo^T
    const int cL = (t & 15) * 4, kB = (t >> 4) * 16;
    const float* wp = Wo + (size_t)kB * D_ + c0B + cL;
#pragma unroll
    for (int u = 0; u < 4; ++u) {
      const int k0 = kB + 4 * u;
      const f32x4 w0 = *(const f32x4*)(wp + (size_t)(4 * u + 0) * D_);
      const f32x4 w1 = *(const f32x4*)(wp + (size_t)(4 * u + 1) * D_);
      const f32x4 w2 = *(const f32x4*)(wp + (size_t)(4 * u + 2) * D_);
      const f32x4 w3 = *(const f32x4*)(wp + (size_t)(4 * u + 3) * D_);
#pragma unroll
      for (int cc = 0; cc < 4; ++cc) {
        const int c = cL + cc;
        uint2 v;
        v.x = cvtpk_bf16(w0[cc], w1[cc]);
        v.y = cvtpk_bf16(w2[cc], w3[cc]);
        *(uint2*)(wsT + c * 256 + (((k0 >> 3) ^ (c & 7)) * 8) + (k0 & 7)) = v;
      }
    }
  }
  {  // stage A = (opart0 + opart1) * (1/l), bf16 swizzled
    const int nL = t >> 2, k64 = (t & 3) * 64;
    const int gn = n0B + nL;
    const int h0 = k64 >> 5;
    float l0s = 0.f, l1s = 0.f;
#pragma unroll
    for (int sp = 0; sp < SPLITS; ++sp) {
      l0s += lpart[((size_t)sp * (B_ * N_) + gn) * H_ + h0];
      l1s += lpart[((size_t)sp * (B_ * N_) + gn) * H_ + h0 + 1];
    }
    const float il0 = 1.f / l0s, il1 = 1.f / l1s;
    const float* obase = opart + (size_t)gn * D_ + k64;
#pragma unroll
    for (int m = 0; m < 8; ++m) {
      f32x4 a = {0.f, 0.f, 0.f, 0.f};
      f32x4 b2 = {0.f, 0.f, 0.f, 0.f};
#pragma unroll
      for (int sp = 0; sp < SPLITS; ++sp) {
        const float* op = obase + (size_t)sp * (B_ * N_) * D_;
        a += *(const f32x4*)(op + 8 * m);
        b2 += *(const f32x4*)(op + 8 * m + 4);
      }
      const float il = (m < 4) ? il0 : il1;
      a *= il;
      b2 *= il;
      uint4 v;
      v.x = cvtpk_bf16(a[0], a[1]);
      v.y = cvtpk_bf16(a[2], a[3]);
      v.z = cvtpk_bf16(b2[0], b2[1]);
      v.w = cvtpk_bf16(b2[2], b2[3]);
      const int k0 = k64 + 8 * m;
      *(uint4*)(xs + nL * 256 + (((k0 >> 3) ^ (nL & 7)) * 8)) = v;
    }
  }
  __syncthreads();

  const int wv = t >> 6, lane = t & 63, lr = lane & 15, lg = lane >> 4;
  const f32x4 zz = {0.f, 0.f, 0.f, 0.f};
  f32x4 acc[4] = {zz, zz, zz, zz};
  const int arow = wv * 16 + lr;
#pragma unroll
  for (int ks = 0; ks < 8; ++ks) {
    const short8 a = *(const short8*)(xs + arow * 256 + (((ks * 4 + lg) ^ (arow & 7)) * 8));
#pragma unroll
    for (int ng = 0; ng < 4; ++ng) {
      const int brow = ng * 16 + lr;
      const short8 bfr = *(const short8*)(wsT + brow * 256 + (((ks * 4 + lg) ^ (brow & 7)) * 8));
      acc[ng] = __builtin_amdgcn_mfma_f32_16x16x32_bf16(a, bfr, acc[ng], 0, 0, 0);
    }
  }
  // D layout: col(lr)=c, row(lg*4+j)=n -> coalesced f32 stores
#pragma unroll
  for (int ng = 0; ng < 4; ++ng) {
    const int c = c0B + ng * 16 + lr;
    const float bb = bo[c];
#pragma unroll
    for (int j = 0; j < 4; ++j)
      out[(size_t)(n0B + wv * 16 + lg * 4 + j) * D_ + c] = acc[ng][j] + bb;
  }
}

extern "C" void kernel_launch(void* const* d_in, const int* in_sizes, int n_in,
                              void* d_out, int out_size, void* d_ws, size_t ws_size,
                              hipStream_t stream) {
  (void)in_sizes; (void)n_in; (void)out_size; (void)ws_size;
  const float* queries  = (const float*)d_in[0];
  const float* keys     = (const float*)d_in[1];
  const float* values   = (const float*)d_in[2];
  const float* presence = (const float*)d_in[3];
  const float* Wq = (const float*)d_in[4];
  const float* bq = (const float*)d_in[5];
  const float* Wk = (const float*)d_in[6];
  const float* bk = (const float*)d_in[7];
  const float* Wv = (const float*)d_in[8];
  const float* bv = (const float*)d_in[9];
  const float* Wo = (const float*)d_in[10];
  const float* bo = (const float*)d_in[11];

  // ws: qb 2MB | kb 2MB | vtb 2MB | opart 8MB | lpart 256KB
  u16* qb  = (u16*)d_ws;
  u16* kb  = qb + (size_t)B_ * H_ * N_ * DH_;
  u16* vtb = kb + (size_t)B_ * H_ * M_ * DH_;
  float* opart = (float*)(vtb + (size_t)B_ * H_ * DH_ * M_);
  float* lpart = opart + (size_t)SPLITS * B_ * N_ * D_;

  qkvproj_kernel<<<dim3(256, 3), 256, 0, stream>>>(
      queries, keys, values, Wq, Wk, Wv, bq, bk, bv, qb, kb, vtb);
  attn_kernel<<<SPLITS * 16 * 32, 256, 0, stream>>>(qb, kb, vtb, presence, opart, lpart);
  projo_kernel<<<256, 256, 0, stream>>>(opart, lpart, Wo, bo, (float*)d_out);
}

// Round 15
// 44.462 us; speedup vs baseline: 2.3534x; 1.0381x over previous
//
#include <hip/hip_runtime.h>

#define B_ 2
#define N_ 2048
#define M_ 2048
#define D_ 256
#define H_ 8
#define DH_ 32
#define SPLITS 2
// 1/sqrt(32) * log2(e): fold into q projection; attention works in exp2 domain
#define QSCALE (0.17677669529663689f * 1.4426950408889634f)

typedef __attribute__((ext_vector_type(8))) short short8;
typedef __attribute__((ext_vector_type(4))) float f32x4;
typedef unsigned short u16;
typedef unsigned int u32;

#if __has_builtin(__builtin_amdgcn_exp2f)
#define EXP2 __builtin_amdgcn_exp2f
#else
#define EXP2 exp2f
#endif

union u4s8 { uint4 u; short8 s; };

__device__ __forceinline__ u16 f2bf(float f) {
  u32 u = __float_as_uint(f);
  return (u16)((u + 0x7fffu + ((u >> 16) & 1u)) >> 16);  // RNE
}
__device__ __forceinline__ u32 cvtpk_bf16(float lo, float hi) {
  u32 r;
  asm("v_cvt_pk_bf16_f32 %0, %1, %2" : "=v"(r) : "v"(lo), "v"(hi));
  return r;
}
__device__ __forceinline__ void gload_lds16(const u16* g, u16* l) {
  __builtin_amdgcn_global_load_lds((const __attribute__((address_space(1))) void*)g,
                                   (__attribute__((address_space(3))) void*)l, 16, 0, 0);
}
__device__ __forceinline__ void gload_lds16f(const float* g, float* l) {
  __builtin_amdgcn_global_load_lds((const __attribute__((address_space(1))) void*)g,
                                   (__attribute__((address_space(3))) void*)l, 16, 0, 0);
}

// ---------- K1: fused q/k/v projection (r7 version, best measured) ----------
__global__ __launch_bounds__(256, 2) void qkvproj_kernel(
    const float* __restrict__ Xq, const float* __restrict__ Xk, const float* __restrict__ Xv,
    const float* __restrict__ Wq, const float* __restrict__ Wk, const float* __restrict__ Wv,
    const float* __restrict__ bq, const float* __restrict__ bk, const float* __restrict__ bv,
    u16* __restrict__ qb, u16* __restrict__ kb, u16* __restrict__ vtb) {
  __shared__ u16 wsT[64 * 256];  // [c][k] = W[k][c], 16B-slot swizzle (k>>3)^(c&7)
  __shared__ u16 xs[64 * 256];   // [n][k] = X[n][k], swizzle (k>>3)^(n&7)
  const int p = blockIdx.y;
  const int nb = blockIdx.x & 63, cb = blockIdx.x >> 6;
  const int n0B = nb * 64, c0B = cb * 64;
  const float* X = p == 0 ? Xq : (p == 1 ? Xk : Xv);
  const float* W = p == 0 ? Wq : (p == 1 ? Wk : Wv);
  const float* bias = p == 0 ? bq : (p == 1 ? bk : bv);
  const int t = threadIdx.x;

  {  // stage W^T
    const int cL = (t & 15) * 4, kB = (t >> 4) * 16;
    const float* wp = W + (size_t)kB * D_ + c0B + cL;
#pragma unroll
    for (int u = 0; u < 4; ++u) {
      const int k0 = kB + 4 * u;
      const f32x4 w0 = *(const f32x4*)(wp + (size_t)(4 * u + 0) * D_);
      const f32x4 w1 = *(const f32x4*)(wp + (size_t)(4 * u + 1) * D_);
      const f32x4 w2 = *(const f32x4*)(wp + (size_t)(4 * u + 2) * D_);
      const f32x4 w3 = *(const f32x4*)(wp + (size_t)(4 * u + 3) * D_);
#pragma unroll
      for (int cc = 0; cc < 4; ++cc) {
        const int c = cL + cc;
        uint2 v;
        v.x = cvtpk_bf16(w0[cc], w1[cc]);
        v.y = cvtpk_bf16(w2[cc], w3[cc]);
        *(uint2*)(wsT + c * 256 + (((k0 >> 3) ^ (c & 7)) * 8) + (k0 & 7)) = v;
      }
    }
  }
  {  // stage X
    const int nL = t >> 2, k64 = (t & 3) * 64;
    const float* xp = X + (size_t)(n0B + nL) * D_ + k64;
#pragma unroll
    for (int m = 0; m < 8; ++m) {
      const f32x4 a = *(const f32x4*)(xp + 8 * m);
      const f32x4 b2 = *(const f32x4*)(xp + 8 * m + 4);
      uint4 v;
      v.x = cvtpk_bf16(a[0], a[1]);
      v.y = cvtpk_bf16(a[2], a[3]);
      v.z = cvtpk_bf16(b2[0], b2[1]);
      v.w = cvtpk_bf16(b2[2], b2[3]);
      const int k0 = k64 + 8 * m;
      *(uint4*)(xs + nL * 256 + (((k0 >> 3) ^ (nL & 7)) * 8)) = v;
    }
  }
  __syncthreads();

  const int wv = t >> 6, lane = t & 63, lr = lane & 15, lg = lane >> 4;
  const f32x4 zz = {0.f, 0.f, 0.f, 0.f};
  f32x4 acc[4] = {zz, zz, zz, zz};
  const int arow = wv * 16 + lr;
#pragma unroll
  for (int ks = 0; ks < 8; ++ks) {
    const short8 a = *(const short8*)(wsT + arow * 256 + (((ks * 4 + lg) ^ (arow & 7)) * 8));
#pragma unroll
    for (int ng = 0; ng < 4; ++ng) {
      const int brow = ng * 16 + lr;
      const short8 b = *(const short8*)(xs + brow * 256 + (((ks * 4 + lg) ^ (brow & 7)) * 8));
      acc[ng] = __builtin_amdgcn_mfma_f32_16x16x32_bf16(a, b, acc[ng], 0, 0, 0);
    }
  }

  // D layout: col(lr)=n, row(lg*4+j)=c
  const int cg4 = c0B + wv * 16 + lg * 4;
  const f32x4 bias4 = *(const f32x4*)(bias + cg4);
  if (p < 2) {
    u16* ob = p == 0 ? qb : kb;
    const float sc = p == 0 ? QSCALE : 1.0f;
#pragma unroll
    for (int ng = 0; ng < 4; ++ng) {
      const int n = n0B + ng * 16 + lr;
      const int b = n >> 11, nn = n & (N_ - 1);
#pragma unroll
      for (int j = 0; j < 4; ++j) {
        const int c = cg4 + j;
        ob[((size_t)(b * H_ + (c >> 5)) * N_ + nn) * DH_ + (c & 31)] =
            f2bf((acc[ng][j] + bias4[j]) * sc);
      }
    }
  } else {
#pragma unroll
    for (int ng = 0; ng < 4; ++ng) {
      const int n = n0B + ng * 16 + lr;
      const int b = n >> 11, nn = n & (M_ - 1);
#pragma unroll
      for (int j = 0; j < 4; ++j) {
        const int c = cg4 + j;
        vtb[((size_t)(b * H_ + (c >> 5)) * DH_ + (c & 31)) * M_ + nn] =
            f2bf(acc[ng][j] + bias4[j]);
      }
    }
  }
}

// ---------- K2: flash attention (no-max, key-split 2; P stays in registers) ----
// grid = 2 splits x 16 bh x 32 qtiles = 1024 blocks (4/CU); 4 waves, 16 q each.
// Per 64-key chunk: K/V staged once per block (global_load_lds, dbuf, prefetch);
// S^T = mfma(K,Q); exp2 * presence (LDS broadcast); P packed bf16 in REGISTERS
// and used directly as the PV A-fragment under a permuted key<->slot mapping
// kappa(lg,j) = {lg*4+j (j<4), 16+lg*4+j-4} (+32 for 2nd MFMA); V B-fragments
// read in the SAME kappa order as 8 conflict-free ds_read_b64. No P LDS.
__global__ __launch_bounds__(256, 4) void attn_kernel(
    const u16* __restrict__ qb, const u16* __restrict__ kb,
    const u16* __restrict__ vtb, const float* __restrict__ presence,
    float* __restrict__ opart, float* __restrict__ lpart) {
  __shared__ u16 kvlds[2][4096];  // [buf]: K[64 keys][32 d] swz | V[32 d][64 keys] swz
  __shared__ float prlds[1024];   // presence slice (f32)
  const int t = threadIdx.x;
  const int wv = t >> 6, lane = t & 63;
  const int lr = lane & 15, lg = lane >> 4;
  const int s = blockIdx.x >> 9;
  const int bh = (blockIdx.x >> 5) & 15;
  const int qblk = blockIdx.x & 31;
  const int b = bh >> 3, h = bh & 7;
  const int n0 = qblk * 64 + wv * 16;
  const int m0 = s * (M_ / SPLITS);
  const int NI = (M_ / SPLITS) / 64;  // 16 chunks

  // staging sources (per-lane, pre-swizzled)
  const int gsk = (t & 3) ^ ((t >> 3) & 3);
  const u16* kst = kb + ((size_t)bh * M_ + m0 + (t >> 2)) * DH_ + gsk * 8;
  const int gsv = (t & 7) ^ ((t >> 3) & 7);
  const u16* vst = vtb + ((size_t)bh * DH_ + (t >> 3)) * M_ + m0 + gsv * 8;
  u16* const ldswK = &kvlds[0][0] + wv * 512;         // + buf*4096
  u16* const ldswV = &kvlds[0][0] + 2048 + wv * 512;  // + buf*4096

  // per-lane LDS fragment read offsets (u16 units)
  const int ko0 = lr * 32 + (lg ^ ((lr >> 1) & 3)) * 8;  // K: + tt*512
  const int sw = lr & 7;
  // V kappa-order piece base: slot (lg>>1)^sw, half lg&1; pieces at ^{0,16,32,48}
  const int vb = (((lg >> 1) ^ sw) * 8) + (lg & 1) * 4;

  // Q as B-frag of S^T: col=query=lr, k=d=lg*8+j
  const short8 qf = *(const short8*)(qb + ((size_t)bh * N_ + n0 + lr) * DH_ + lg * 8);

  const f32x4 zz = {0.f, 0.f, 0.f, 0.f};
  f32x4 o0 = zz, o1 = zz, racc = zz;

  gload_lds16(kst, ldswK);  // chunk 0 -> buf 0
  gload_lds16(vst, ldswV);
  gload_lds16f(presence + (size_t)b * M_ + m0 + wv * 256 + lane * 4, prlds + wv * 256);
  __syncthreads();

#pragma unroll 2
  for (int i = 0; i < NI; ++i) {
    const int mm = i * 64;
    const u16* kl = &kvlds[i & 1][0];
    const u16* vl = &kvlds[i & 1][2048];
    if (i + 1 < NI) {  // prefetch chunk i+1 into other buffer
      const int bo = ((i + 1) & 1) * 4096;
      gload_lds16(kst + (size_t)(i + 1) * (64 * DH_), ldswK + bo);
      gload_lds16(vst + (size_t)(i + 1) * 64, ldswV + bo);
    }

    f32x4 s4[4];
    __builtin_amdgcn_s_setprio(1);
#pragma unroll
    for (int tt = 0; tt < 4; ++tt) {
      const short8 kf = *(const short8*)(kl + tt * 512 + ko0);
      s4[tt] = __builtin_amdgcn_mfma_f32_16x16x32_bf16(kf, qf, zz, 0, 0, 0);
    }
    __builtin_amdgcn_s_setprio(0);

    // softmax (no max) + presence, pack P directly into A-frags (kappa order)
#pragma unroll
    for (int tt = 0; tt < 4; ++tt) {
      const f32x4 pr = *(const f32x4*)(prlds + mm + tt * 16 + lg * 4);  // broadcast
#pragma unroll
      for (int j = 0; j < 4; ++j) s4[tt][j] = EXP2(s4[tt][j]);
      s4[tt] *= pr;  // exact 0 when masked, identity when present
      racc += s4[tt];
    }
    u4s8 pm0, pm1;
    pm0.u.x = cvtpk_bf16(s4[0][0], s4[0][1]);  // keys lg*4+{0,1}
    pm0.u.y = cvtpk_bf16(s4[0][2], s4[0][3]);  // keys lg*4+{2,3}
    pm0.u.z = cvtpk_bf16(s4[1][0], s4[1][1]);  // keys 16+lg*4+{0,1}
    pm0.u.w = cvtpk_bf16(s4[1][2], s4[1][3]);
    pm1.u.x = cvtpk_bf16(s4[2][0], s4[2][1]);  // keys 32+lg*4+{0,1}
    pm1.u.y = cvtpk_bf16(s4[2][2], s4[2][3]);
    pm1.u.z = cvtpk_bf16(s4[3][0], s4[3][1]);  // keys 48+lg*4+{0,1}
    pm1.u.w = cvtpk_bf16(s4[3][2], s4[3][3]);

    // V B-frags in kappa order: rows d=lr (o0) and d=16+lr (o1), 8B pieces
    const u16* vr0 = vl + lr * 64;
    const u16* vr1 = vl + (16 + lr) * 64;
    u4s8 vm0, vm1, vm2, vm3;
    {
      const uint2 e0 = *(const uint2*)(vr0 + (vb ^ 0));   // keys lg*4+{0..3}
      const uint2 e1 = *(const uint2*)(vr0 + (vb ^ 16));  // keys 16+lg*4+{0..3}
      const uint2 e2 = *(const uint2*)(vr0 + (vb ^ 32));  // keys 32+...
      const uint2 e3 = *(const uint2*)(vr0 + (vb ^ 48));  // keys 48+...
      vm0.u = make_uint4(e0.x, e0.y, e1.x, e1.y);
      vm1.u = make_uint4(e2.x, e2.y, e3.x, e3.y);
      const uint2 f0 = *(const uint2*)(vr1 + (vb ^ 0));
      const uint2 f1 = *(const uint2*)(vr1 + (vb ^ 16));
      const uint2 f2 = *(const uint2*)(vr1 + (vb ^ 32));
      const uint2 f3 = *(const uint2*)(vr1 + (vb ^ 48));
      vm2.u = make_uint4(f0.x, f0.y, f1.x, f1.y);
      vm3.u = make_uint4(f2.x, f2.y, f3.x, f3.y);
    }
    __builtin_amdgcn_s_setprio(1);
    o0 = __builtin_amdgcn_mfma_f32_16x16x32_bf16(pm0.s, vm0.s, o0, 0, 0, 0);
    o0 = __builtin_amdgcn_mfma_f32_16x16x32_bf16(pm1.s, vm1.s, o0, 0, 0, 0);
    o1 = __builtin_amdgcn_mfma_f32_16x16x32_bf16(pm0.s, vm2.s, o1, 0, 0, 0);
    o1 = __builtin_amdgcn_mfma_f32_16x16x32_bf16(pm1.s, vm3.s, o1, 0, 0, 0);
    __builtin_amdgcn_s_setprio(0);
    __syncthreads();
  }

  float l = (racc[0] + racc[1]) + (racc[2] + racc[3]);
  l += __shfl_xor(l, 16);
  l += __shfl_xor(l, 32);
  if (lg == 0) lpart[((size_t)s * (B_ * N_) + b * N_ + n0 + lr) * H_ + h] = l;

  float* ob = opart + ((size_t)s * (B_ * N_) + (size_t)b * N_ + n0) * D_ + h * DH_;
#pragma unroll
  for (int j = 0; j < 4; ++j) {
    const int q = lg * 4 + j;
    ob[(size_t)q * D_ + lr] = o0[j];
    ob[(size_t)q * D_ + 16 + lr] = o1[j];
  }
}

// ---------- K3: output projection (combine 2 splits, normalize, MFMA) ----------
__global__ __launch_bounds__(256, 2) void projo_kernel(
    const float* __restrict__ opart, const float* __restrict__ lpart,
    const float* __restrict__ Wo, const float* __restrict__ bo,
    float* __restrict__ out) {
  __shared__ u16 wsT[64 * 256];  // Wo^T [c][k] swizzled
  __shared__ u16 xs[64 * 256];   // normalized attention output [n][k] swizzled
  const int nb = blockIdx.x & 63, cb = blockIdx.x >> 6;
  const int n0B = nb * 64, c0B = cb * 64;
  const int t = threadIdx.x;

  {  // stage Wo^T
    const int cL = (t & 15) * 4, kB = (t >> 4) * 16;
    const float* wp = Wo + (size_t)kB * D_ + c0B + cL;
#pragma unroll
    for (int u = 0; u < 4; ++u) {
      const int k0 = kB + 4 * u;
      const f32x4 w0 = *(const f32x4*)(wp + (size_t)(4 * u + 0) * D_);
      const f32x4 w1 = *(const f32x4*)(wp + (size_t)(4 * u + 1) * D_);
      const f32x4 w2 = *(const f32x4*)(wp + (size_t)(4 * u + 2) * D_);
      const f32x4 w3 = *(const f32x4*)(wp + (size_t)(4 * u + 3) * D_);
#pragma unroll
      for (int cc = 0; cc < 4; ++cc) {
        const int c = cL + cc;
        uint2 v;
        v.x = cvtpk_bf16(w0[cc], w1[cc]);
        v.y = cvtpk_bf16(w2[cc], w3[cc]);
        *(uint2*)(wsT + c * 256 + (((k0 >> 3) ^ (c & 7)) * 8) + (k0 & 7)) = v;
      }
    }
  }
  {  // stage A = (opart0 + opart1) * (1/l), bf16 swizzled
    const int nL = t >> 2, k64 = (t & 3) * 64;
    const int gn = n0B + nL;
    const int h0 = k64 >> 5;
    float l0s = 0.f, l1s = 0.f;
#pragma unroll
    for (int sp = 0; sp < SPLITS; ++sp) {
      l0s += lpart[((size_t)sp * (B_ * N_) + gn) * H_ + h0];
      l1s += lpart[((size_t)sp * (B_ * N_) + gn) * H_ + h0 + 1];
    }
    const float il0 = 1.f / l0s, il1 = 1.f / l1s;
    const float* obase = opart + (size_t)gn * D_ + k64;
#pragma unroll
    for (int m = 0; m < 8; ++m) {
      f32x4 a = {0.f, 0.f, 0.f, 0.f};
      f32x4 b2 = {0.f, 0.f, 0.f, 0.f};
#pragma unroll
      for (int sp = 0; sp < SPLITS; ++sp) {
        const float* op = obase + (size_t)sp * (B_ * N_) * D_;
        a += *(const f32x4*)(op + 8 * m);
        b2 += *(const f32x4*)(op + 8 * m + 4);
      }
      const float il = (m < 4) ? il0 : il1;
      a *= il;
      b2 *= il;
      uint4 v;
      v.x = cvtpk_bf16(a[0], a[1]);
      v.y = cvtpk_bf16(a[2], a[3]);
      v.z = cvtpk_bf16(b2[0], b2[1]);
      v.w = cvtpk_bf16(b2[2], b2[3]);
      const int k0 = k64 + 8 * m;
      *(uint4*)(xs + nL * 256 + (((k0 >> 3) ^ (nL & 7)) * 8)) = v;
    }
  }
  __syncthreads();

  const int wv = t >> 6, lane = t & 63, lr = lane & 15, lg = lane >> 4;
  const f32x4 zz = {0.f, 0.f, 0.f, 0.f};
  f32x4 acc[4] = {zz, zz, zz, zz};
  const int arow = wv * 16 + lr;
#pragma unroll
  for (int ks = 0; ks < 8; ++ks) {
    const short8 a = *(const short8*)(xs + arow * 256 + (((ks * 4 + lg) ^ (arow & 7)) * 8));
#pragma unroll
    for (int ng = 0; ng < 4; ++ng) {
      const int brow = ng * 16 + lr;
      const short8 bfr = *(const short8*)(wsT + brow * 256 + (((ks * 4 + lg) ^ (brow & 7)) * 8));
      acc[ng] = __builtin_amdgcn_mfma_f32_16x16x32_bf16(a, bfr, acc[ng], 0, 0, 0);
    }
  }
  // D layout: col(lr)=c, row(lg*4+j)=n -> coalesced f32 stores
#pragma unroll
  for (int ng = 0; ng < 4; ++ng) {
    const int c = c0B + ng * 16 + lr;
    const float bb = bo[c];
#pragma unroll
    for (int j = 0; j < 4; ++j)
      out[(size_t)(n0B + wv * 16 + lg * 4 + j) * D_ + c] = acc[ng][j] + bb;
  }
}

extern "C" void kernel_launch(void* const* d_in, const int* in_sizes, int n_in,
                              void* d_out, int out_size, void* d_ws, size_t ws_size,
                              hipStream_t stream) {
  (void)in_sizes; (void)n_in; (void)out_size; (void)ws_size;
  const float* queries  = (const float*)d_in[0];
  const float* keys     = (const float*)d_in[1];
  const float* values   = (const float*)d_in[2];
  const float* presence = (const float*)d_in[3];
  const float* Wq = (const float*)d_in[4];
  const float* bq = (const float*)d_in[5];
  const float* Wk = (const float*)d_in[6];
  const float* bk = (const float*)d_in[7];
  const float* Wv = (const float*)d_in[8];
  const float* bv = (const float*)d_in[9];
  const float* Wo = (const float*)d_in[10];
  const float* bo = (const float*)d_in[11];

  // ws: qb 2MB | kb 2MB | vtb 2MB | opart 8MB | lpart 256KB
  u16* qb  = (u16*)d_ws;
  u16* kb  = qb + (size_t)B_ * H_ * N_ * DH_;
  u16* vtb = kb + (size_t)B_ * H_ * M_ * DH_;
  float* opart = (float*)(vtb + (size_t)B_ * H_ * DH_ * M_);
  float* lpart = opart + (size_t)SPLITS * B_ * N_ * D_;

  qkvproj_kernel<<<dim3(256, 3), 256, 0, stream>>>(
      queries, keys, values, Wq, Wk, Wv, bq, bk, bv, qb, kb, vtb);
  attn_kernel<<<SPLITS * 16 * 32, 256, 0, stream>>>(qb, kb, vtb, presence, opart, lpart);
  projo_kernel<<<256, 256, 0, stream>>>(opart, lpart, Wo, bo, (float*)d_out);
}